// Round 6
// baseline (351.696 us; speedup 1.0000x reference)
//
#include <hip/hip_runtime.h>
#include <hip/hip_bf16.h>

typedef __attribute__((ext_vector_type(4))) float f32x4;
typedef __attribute__((ext_vector_type(8))) short bf16x8;

#define NEG_L2K (-0.025952563241307517f)  // -log2(10000)/512

#define VMW(N) asm volatile("s_waitcnt vmcnt(" #N ")" ::: "memory")
#define SCHB() __builtin_amdgcn_sched_barrier(0)
#define SBAR() __builtin_amdgcn_s_barrier()

__device__ __forceinline__ unsigned short f2bf(float f) {
    union { float f; unsigned int u; } v; v.f = f;
    unsigned int r = v.u + 0x7FFFu + ((v.u >> 16) & 1u);
    return (unsigned short)(r >> 16);
}

__device__ __forceinline__ f32x4 MFMA(bf16x8 a, bf16x8 b, f32x4 c) {
    return __builtin_amdgcn_mfma_f32_16x16x32_bf16(a, b, c, 0, 0, 0);
}

// async global->VGPR 16B load; volatile pins issue order so the manual vmcnt
// ledger stays valid.  Consumed only after the matching VMW.
__device__ __forceinline__ bf16x8 gload16(const unsigned short* p) {
    bf16x8 r;
    asm volatile("global_load_dwordx4 %0, %1, off" : "=v"(r) : "v"(p) : "memory");
    return r;
}

// ---------------- Kernel 1: X fp32 -> bf16 (same layout); zero A[8192] ----
__global__ void prep_x_kernel(const float* __restrict__ X,
                              unsigned short* __restrict__ Xb,
                              float* __restrict__ A, int n8) {
    int gid = blockIdx.x * blockDim.x + threadIdx.x;
    if (gid < 8192) A[gid] = 0.0f;
    int stride = gridDim.x * blockDim.x;
    for (int i = gid; i < n8; i += stride) {
        float4 a = ((const float4*)X)[2 * i];
        float4 b = ((const float4*)X)[2 * i + 1];
        union { unsigned short us[8]; uint4 v; } o;
        o.us[0] = f2bf(a.x); o.us[1] = f2bf(a.y);
        o.us[2] = f2bf(a.z); o.us[3] = f2bf(a.w);
        o.us[4] = f2bf(b.x); o.us[5] = f2bf(b.y);
        o.us[6] = f2bf(b.z); o.us[7] = f2bf(b.w);
        ((uint4*)Xb)[i] = o.v;
    }
}

// ---------------- Kernel 2: W [2048][4096] fp32 -> fragment-major bf16 ----
// Wf element (f,k) stored at ((g*64+c)*64 + hi*16+lr)*8 + e8 where
// g=f>>4, lr=f&15, c=k>>5, hi=(k>>3)&3, e8=k&7.  A wave's MFMA B-fragment
// (16 cols x 32 k) is then 64 lanes x 16B contiguous -> one coalesced load.
__global__ __launch_bounds__(256) void prep_w_kernel(const float* __restrict__ W,
                                                     unsigned short* __restrict__ Wf) {
    __shared__ unsigned short t[64][64];  // t[k_local][f_local]
    int f0 = blockIdx.x * 64;   // along 4096 (f)
    int k0 = blockIdx.y * 64;   // along 2048 (k)
    int tx = threadIdx.x & 63;
    int ty = threadIdx.x >> 6;  // 0..3
    for (int j = 0; j < 64; j += 4)
        t[ty + j][tx] = f2bf(W[(size_t)(k0 + ty + j) * 4096 + f0 + tx]);
    __syncthreads();
    const int f = f0 + tx;
    const int g = f >> 4, lr = f & 15;
    #pragma unroll
    for (int j = 0; j < 2; ++j) {
        int kl = ty * 16 + j * 8;           // 0..63 step 8
        int k  = k0 + kl;
        int c  = k >> 5, hi = (k >> 3) & 3;
        union { unsigned short us[8]; uint4 v; } o;
        #pragma unroll
        for (int e8 = 0; e8 < 8; ++e8) o.us[e8] = t[kl + e8][tx];
        *(uint4*)(Wf + ((((size_t)g << 6) | c) << 9) + (((hi << 4) | lr) << 3)) = o.v;
    }
}

// ---- staging helper: one 128-row x 64-col bf16 tile (16 KB), 2 loads/thread
// LDS dest linear; global source pre-swizzled (chunk jl = jp ^ (row&7)) so the
// swizzled ds_reads (T2) see the right data.
__device__ __forceinline__ void stage128(const unsigned short* __restrict__ g,
                                         unsigned short* lds, int tid) {
    int lane = tid & 63, w = tid >> 6;
    #pragma unroll
    for (int q = 0; q < 2; ++q) {
        int c = (q * 8 + w) * 64 + lane;          // physical 16B-chunk id
        int row = c >> 3;
        int jl = (c & 7) ^ (row & 7);             // logical chunk in row
        __builtin_amdgcn_global_load_lds(
            (const __attribute__((address_space(1))) void*)(g + (size_t)row * 2048 + jl * 8),
            (__attribute__((address_space(3))) void*)(lds + c * 8), 16, 0, 0);
    }
}

// ---------------- Kernel 3: fused GEMM + rotary + cos*cos + col-reduce ----
// A in LDS (T2-swizzled, dbuf 64 KiB); B (K,V) double-buffered in REGISTERS
// via coalesced fragment-major loads.  One VMW(12) + 2 barriers per K-step.
// Ledger: before P0 of tile t: 12 outstanding (A4+BK4+BV4 of t); issue 12 for
// t+1 -> 24; VMW(12) drains exactly tile t's.
__global__ __launch_bounds__(512, 2) void gemm_acos_kernel(
    const unsigned short* __restrict__ Xb,   // [16384][2048]
    const unsigned short* __restrict__ Wf,   // fragment-major [4096x2048]
    const float* __restrict__ bias,          // [4096]
    float* __restrict__ A)                   // [4][2048]
{
    __shared__ __align__(16) unsigned short Als[2][256 * 64];  // 64 KB

    const int tid  = threadIdx.x;
    const int lane = tid & 63;
    const int wid  = tid >> 6;    // 0..7
    const int wr   = wid >> 2;    // 0..1  (row half: 128 rows)
    const int wc   = wid & 3;     // 0..3  (col quarter: 32 cols)
    const int lr   = lane & 15;
    const int hi   = lane >> 4;   // 0..3
    const int e    = lane & 7;

    // T1: bijective XCD swizzle, grid 1024 = 64 mtiles x 16 ntiles, ntile-major
    const int orig  = blockIdx.x;
    const int wg    = (orig & 7) * 128 + (orig >> 3);
    const int mtile = wg & 63;
    const int ntile = wg >> 6;
    const int row0  = mtile * 256;
    const int n0    = ntile * 128;

    const unsigned short* gA = Xb + (size_t)row0 * 2048;
    // fragment-major B bases: group G = ntile*8 + wc*2 + n; V at G+128.
    const unsigned short* baseK = Wf + (((size_t)(ntile * 8 + wc * 2) * 64) << 3) * 64 + lane * 8;
    const unsigned short* baseV = baseK + ((size_t)128 * 64 * 512);

    f32x4 accK[8][2] = {};
    f32x4 accV[8][2] = {};

    // ds_read byte offsets (T2-swizzled chunk: (ks*4+hi) ^ (lane&7))
    const int aoff = (wr * 128 + lr) * 128;
    const int x0   = ((0 + hi) ^ e) * 16;
    const int x1   = ((4 + hi) ^ e) * 16;

    bf16x8 bkA[2][2], bvA[2][2], bkB[2][2], bvB[2][2];

    // prologue: tile 0 = [A:4, BK:4, BV:4] -> 12 outstanding
    stage128(gA,              Als[0],            tid);
    stage128(gA + 128 * 2048, Als[0] + 128 * 64, tid);
    #pragma unroll
    for (int n = 0; n < 2; ++n)
        #pragma unroll
        for (int ck = 0; ck < 2; ++ck)
            bkA[n][ck] = gload16(baseK + (((size_t)(n * 64 + ck)) << 9));
    #pragma unroll
    for (int n = 0; n < 2; ++n)
        #pragma unroll
        for (int ck = 0; ck < 2; ++ck)
            bvA[n][ck] = gload16(baseV + (((size_t)(n * 64 + ck)) << 9));

    #pragma unroll 1
    for (int it = 0; it < 16; ++it) {
        #pragma unroll
        for (int sub = 0; sub < 2; ++sub) {
            const int kt  = (it * 2 + sub) * 64;
            const bool last = (kt == 2048 - 64);
            const int cur = sub;                     // buffer parity == sub
            const char* As = (const char*)Als[cur];
            unsigned short* An = Als[cur ^ 1];
            const int ktn = kt + 64;
            const int c0n = ktn >> 5;
            bf16x8 (&bkC)[2][2] = sub ? bkB : bkA;   // current (static index)
            bf16x8 (&bvC)[2][2] = sub ? bvB : bvA;
            bf16x8 (&bkN)[2][2] = sub ? bkA : bkB;   // next
            bf16x8 (&bvN)[2][2] = sub ? bvA : bvB;

            bf16x8 af0[4][2], af1[4][2];

            // ---- P0: issue full next-tile prefetch, single counted wait
            if (!last) {
                stage128(gA + ktn,              An,            tid);
                stage128(gA + 128 * 2048 + ktn, An + 128 * 64, tid);
                #pragma unroll
                for (int n = 0; n < 2; ++n)
                    #pragma unroll
                    for (int ck = 0; ck < 2; ++ck)
                        bkN[n][ck] = gload16(baseK + (((size_t)(n * 64 + c0n + ck)) << 9));
                #pragma unroll
                for (int n = 0; n < 2; ++n)
                    #pragma unroll
                    for (int ck = 0; ck < 2; ++ck)
                        bvN[n][ck] = gload16(baseV + (((size_t)(n * 64 + c0n + ck)) << 9));
                VMW(12);               // drain tile t; leave t+1's 12 in flight
            } else {
                VMW(0);
            }
            SCHB();
            SBAR();                    // tile t's A visible to all waves
            #pragma unroll
            for (int m = 0; m < 4; ++m) {
                af0[m][0] = *(const bf16x8*)(As + aoff + m * 2048 + x0);
                af0[m][1] = *(const bf16x8*)(As + aoff + m * 2048 + x1);
            }
            __builtin_amdgcn_s_setprio(1);
            #pragma unroll
            for (int m = 0; m < 4; ++m)
                #pragma unroll
                for (int n = 0; n < 2; ++n) {
                    accK[m][n] = MFMA(af0[m][0], bkC[n][0], accK[m][n]);
                    accK[m][n] = MFMA(af0[m][1], bkC[n][1], accK[m][n]);
                }
            __builtin_amdgcn_s_setprio(0);

            // ---- P1: V rows m0-3 (pure register MFMA)
            __builtin_amdgcn_s_setprio(1);
            #pragma unroll
            for (int m = 0; m < 4; ++m)
                #pragma unroll
                for (int n = 0; n < 2; ++n) {
                    accV[m][n] = MFMA(af0[m][0], bvC[n][0], accV[m][n]);
                    accV[m][n] = MFMA(af0[m][1], bvC[n][1], accV[m][n]);
                }
            __builtin_amdgcn_s_setprio(0);

            // ---- P2: K rows m4-7; barrier AFTER the consuming MFMAs so all
            // buf[t] ds_reads are landed before anyone stages t+2 into it.
            #pragma unroll
            for (int m = 0; m < 4; ++m) {
                af1[m][0] = *(const bf16x8*)(As + aoff + (m + 4) * 2048 + x0);
                af1[m][1] = *(const bf16x8*)(As + aoff + (m + 4) * 2048 + x1);
            }
            __builtin_amdgcn_s_setprio(1);
            #pragma unroll
            for (int m = 0; m < 4; ++m)
                #pragma unroll
                for (int n = 0; n < 2; ++n) {
                    accK[m + 4][n] = MFMA(af1[m][0], bkC[n][0], accK[m + 4][n]);
                    accK[m + 4][n] = MFMA(af1[m][1], bkC[n][1], accK[m + 4][n]);
                }
            __builtin_amdgcn_s_setprio(0);
            SBAR();                    // all reads of buf[t] complete

            // ---- P3: pure MFMA (V rows m4-7)
            __builtin_amdgcn_s_setprio(1);
            #pragma unroll
            for (int m = 0; m < 4; ++m)
                #pragma unroll
                for (int n = 0; n < 2; ++n) {
                    accV[m + 4][n] = MFMA(af1[m][0], bvC[n][0], accV[m + 4][n]);
                    accV[m + 4][n] = MFMA(af1[m][1], bvC[n][1], accV[m + 4][n]);
                }
            __builtin_amdgcn_s_setprio(0);
        }
    }

    // ---- epilogue: bias, rotary, cos*cos, reduce over rows, atomicAdd
    const int batch = row0 >> 12;
    const int sb    = (row0 & 4095) + wr * 128 + hi * 4;

    #pragma unroll
    for (int n = 0; n < 2; ++n) {
        const int c     = n0 + wc * 32 + n * 16 + lr;   // channel in [0,2048)
        const float bK  = bias[c];
        const float bV  = bias[c + 2048];
        const bool rot  = (c < 1024);
        const float invf = exp2f((float)(c >> 1) * NEG_L2K);
        const float sgn  = (c & 1) ? 1.0f : -1.0f;
        float colsum = 0.0f;
        #pragma unroll
        for (int m = 0; m < 8; ++m) {
            const int srow = sb + m * 16;
            #pragma unroll
            for (int q = 0; q < 4; ++q) {
                float kv = accK[m][n][q] + bK;
                float vv = accV[m][n][q] + bV;
                float pk = __shfl_xor(kv, 1);
                float pv = __shfl_xor(vv, 1);
                float kr = kv, vr = vv;
                if (rot) {
                    float sn, cs;
                    __sincosf((float)(srow + q) * invf, &sn, &cs);
                    float tt = sgn * sn;
                    kr = kv * cs + pk * tt;
                    vr = vv * cs + pv * tt;
                }
                colsum += __cosf(kr) * __cosf(vr);
            }
        }
        colsum += __shfl_xor(colsum, 16);
        colsum += __shfl_xor(colsum, 32);
        if (lane < 16)
            atomicAdd(&A[batch * 2048 + c], colsum);
    }
}

// ---------------- Kernel 4: out = (0.5*A + 0.5) * X --------------------
__global__ void scale_out_kernel(const float* __restrict__ X,
                                 const float* __restrict__ A,
                                 float* __restrict__ out, int n4) {
    int gid = blockIdx.x * blockDim.x + threadIdx.x;
    int stride = gridDim.x * blockDim.x;
    for (int i = gid; i < n4; i += stride) {
        int e0 = i * 4;
        int b  = e0 >> 23;        // S*D = 2^23
        int d  = e0 & 2047;
        float4 a4 = *(const float4*)(A + b * 2048 + d);
        float4 x4 = ((const float4*)X)[i];
        float4 o;
        o.x = (0.5f * a4.x + 0.5f) * x4.x;
        o.y = (0.5f * a4.y + 0.5f) * x4.y;
        o.z = (0.5f * a4.z + 0.5f) * x4.z;
        o.w = (0.5f * a4.w + 0.5f) * x4.w;
        ((float4*)out)[i] = o;
    }
}

extern "C" void kernel_launch(void* const* d_in, const int* in_sizes, int n_in,
                              void* d_out, int out_size, void* d_ws, size_t ws_size,
                              hipStream_t stream) {
    const float* X    = (const float*)d_in[0];   // [4][4096][2048]
    const float* W    = (const float*)d_in[1];   // [2048][4096]
    const float* bias = (const float*)d_in[2];   // [4096]
    float* out = (float*)d_out;

    const size_t szA  = 32768;                       // 4*2048*4 (padded)
    const size_t szWt = (size_t)4096 * 2048 * 2;     // 16.8 MB
    const size_t szXb = (size_t)16384 * 2048 * 2;    // 67.1 MB

    char* ws = (char*)d_ws;
    float* A = (float*)ws;                           // assume ws >= 32 KB
    unsigned short* Wt;
    unsigned short* Xb;
    if (ws_size >= szA + szWt + szXb) {
        Wt = (unsigned short*)(ws + szA);
        Xb = (unsigned short*)(ws + szA + szWt);
    } else if (ws_size >= szA + szWt) {
        Wt = (unsigned short*)(ws + szA);
        Xb = (unsigned short*)d_out;                 // scratch; rewritten by kernel 4
    } else {
        Xb = (unsigned short*)d_out;
        Wt = (unsigned short*)((char*)d_out + szXb); // 67+16.8 MB <= 134 MB
    }

    prep_x_kernel<<<2048, 256, 0, stream>>>(X, Xb, A, 16384 * 2048 / 8);
    prep_w_kernel<<<dim3(64, 32), 256, 0, stream>>>(W, Wt);
    gemm_acos_kernel<<<1024, 512, 0, stream>>>(Xb, Wt, bias, A);
    scale_out_kernel<<<2048, 256, 0, stream>>>(X, A, out, 16384 * 2048 / 4);
}

// Round 7
// 235.409 us; speedup vs baseline: 1.4940x; 1.4940x over previous
//
#include <hip/hip_runtime.h>
#include <hip/hip_bf16.h>

typedef __attribute__((ext_vector_type(4)))  int   i32x4;
typedef __attribute__((ext_vector_type(8)))  int   i32x8;
typedef __attribute__((ext_vector_type(16))) float f32x16;

#define NEG_L2K (-0.025952563241307517f)  // -log2(10000)/512

#define VMW(N) asm volatile("s_waitcnt vmcnt(" #N ")" ::: "memory")
#define SCHB() __builtin_amdgcn_sched_barrier(0)
#define SBAR() __builtin_amdgcn_s_barrier()

#define AS1 __attribute__((address_space(1)))
#define AS3 __attribute__((address_space(3)))

__device__ __forceinline__ unsigned int pk4_fp8(float a, float b, float c, float d) {
    unsigned int v = __builtin_amdgcn_cvt_pk_fp8_f32(a, b, 0, false);
    v = __builtin_amdgcn_cvt_pk_fp8_f32(c, d, v, true);
    return v;
}

// ---------------- Kernel 1: X fp32 -> fp8 in MFMA-fragment-major layout ----
// Xf chunk id g in [0, 2^21): tile = g>>10 (mtile*32+kt), c = g&1023,
// s = c>>6 = wrh*8+mf*2+rd, lane = c&63.
// chunk bytes = fp8(X[mtile*256+wrh*128+mf*32+(lane&31)][kt*64+(lane>>5)*32+rd*16 .. +16])
__global__ __launch_bounds__(256) void prep_x_kernel(const float* __restrict__ X,
                                                     unsigned char* __restrict__ Xf,
                                                     float* __restrict__ A) {
    int g = blockIdx.x * 256 + threadIdx.x;
    if (g < 8192) A[g] = 0.0f;
    int tileid = g >> 10;
    int mtile  = tileid >> 5;
    int kt     = tileid & 31;
    int c      = g & 1023;
    int s      = c >> 6;
    int lane   = c & 63;
    int row  = mtile * 256 + (s >> 3) * 128 + ((s >> 1) & 3) * 32 + (lane & 31);
    int kcol = kt * 64 + (lane >> 5) * 32 + (s & 1) * 16;
    const float* src = X + (size_t)row * 2048 + kcol;
    float4 f0 = *(const float4*)(src);
    float4 f1 = *(const float4*)(src + 4);
    float4 f2 = *(const float4*)(src + 8);
    float4 f3 = *(const float4*)(src + 12);
    uint4 o;
    o.x = pk4_fp8(f0.x, f0.y, f0.z, f0.w);
    o.y = pk4_fp8(f1.x, f1.y, f1.z, f1.w);
    o.z = pk4_fp8(f2.x, f2.y, f2.z, f2.w);
    o.w = pk4_fp8(f3.x, f3.y, f3.z, f3.w);
    *(uint4*)(Xf + (size_t)g * 16) = o;
}

// ---------------- Kernel 2: W fp32 -> fp8 (x16 pre-scale) frag-major -------
// Out tile (ntile, kt, KV) = 8 KB at ((ntile*32+kt)*2+KV)*8192; within:
// chunk (wc*2+rd)*64+lane holds W[kt*64+(lane>>5)*32+rd*16 ..+16][ntile*128+wc*32+(lane&31)]*16
__global__ __launch_bounds__(256) void prep_w_kernel(const float* __restrict__ W,
                                                     unsigned char* __restrict__ Wf) {
    __shared__ unsigned char t[64][72];
    int f0 = blockIdx.x * 64;   // along 4096 (f)
    int k0 = blockIdx.y * 64;   // along 2048 (k)
    int tx = threadIdx.x & 63;
    int ty = threadIdx.x >> 6;
    for (int r = ty; r < 64; r += 4) {
        float w = W[(size_t)(k0 + r) * 4096 + f0 + tx] * 16.0f;
        t[r][tx] = (unsigned char)(__builtin_amdgcn_cvt_pk_fp8_f32(w, w, 0, false) & 0xFF);
    }
    __syncthreads();
    int c   = threadIdx.x;
    int il  = c & 31;
    int lh  = (c >> 5) & 1;
    int rd  = (c >> 6) & 1;
    int wcl = c >> 7;
    int col_l = wcl * 32 + il;          // 0..63 within block
    int kl    = lh * 32 + rd * 16;
    int fh    = f0 & 2047;
    int KV    = f0 >> 11;
    int ntile = fh >> 7;
    int wcg   = ((fh >> 5) & 2) + wcl;
    union { unsigned char b[16]; uint4 v; } ob;
    #pragma unroll
    for (int b = 0; b < 16; ++b) ob.b[b] = t[kl + b][col_l];
    size_t base = ((((size_t)ntile * 32 + blockIdx.y) * 2 + KV) << 13)
                + (size_t)(((wcg * 2 + rd) * 64 + lh * 32 + il) << 4);
    *(uint4*)(Wf + base) = ob.v;
}

// ---------------- Kernel 3: fused fp8 GEMM + rotary + cos*cos + reduce ----
// MX-fp8 mfma_scale 32x32x64 (scales: A=1.0, B=2^-4 undoing W x16).
// LDS fragment-major (linear stage, conflict-free ds_read_b128).
// R5 schedule: 1 counted VMW(4) + 2 barriers per K-step; T1 + T5.
__global__ __launch_bounds__(512, 2) void gemm_acos_kernel(
    const unsigned char* __restrict__ Xf,
    const unsigned char* __restrict__ Wf,
    const float* __restrict__ bias,
    float* __restrict__ A)
{
    __shared__ __align__(16) unsigned char Als[2][16384];
    __shared__ __align__(16) unsigned char Kls[2][8192];
    __shared__ __align__(16) unsigned char Vls[2][8192];

    const int tid  = threadIdx.x;
    const int lane = tid & 63;
    const int wid  = tid >> 6;    // 0..7
    const int wrh  = wid >> 2;    // 0..1  row half (128 rows)
    const int wc   = wid & 3;     // 0..3  col quarter (32 cols)
    const int l31  = lane & 31;
    const int lh   = lane >> 5;

    // T1: bijective XCD swizzle, grid 1024 = 64 mtiles x 16 ntiles
    const int orig  = blockIdx.x;
    const int wg    = (orig & 7) * 128 + (orig >> 3);
    const int mtile = wg & 63;
    const int ntile = wg >> 6;
    const int row0  = mtile * 256;
    const int n0    = ntile * 128;

    const unsigned char* XfT = Xf + ((size_t)(mtile * 32) << 14);
    const unsigned char* WfT = Wf + ((size_t)(ntile * 32) << 14);

    f32x16 accK[4] = {};
    f32x16 accV[4] = {};

    const int abase = (wrh * 512 + lane) * 16;   // + mf*2048 + rd*1024
    const int bbase = (wc * 128 + lane) * 16;    // + rd*1024

    // stage one K-tile (A: 2x8 KB, K: 8 KB, V: 8 KB) -> 4 loads/thread
    #define STAGE(T, NB)                                                                   \
        do {                                                                               \
            const unsigned char* ga = XfT + ((size_t)(T) << 14);                           \
            const unsigned char* gw = WfT + ((size_t)(T) << 14);                           \
            __builtin_amdgcn_global_load_lds((const AS1 void*)(ga + tid * 16),             \
                (AS3 void*)(Als[NB] + tid * 16), 16, 0, 0);                                \
            __builtin_amdgcn_global_load_lds((const AS1 void*)(ga + 8192 + tid * 16),      \
                (AS3 void*)(Als[NB] + 8192 + tid * 16), 16, 0, 0);                         \
            __builtin_amdgcn_global_load_lds((const AS1 void*)(gw + tid * 16),             \
                (AS3 void*)(Kls[NB] + tid * 16), 16, 0, 0);                                \
            __builtin_amdgcn_global_load_lds((const AS1 void*)(gw + 8192 + tid * 16),      \
                (AS3 void*)(Vls[NB] + tid * 16), 16, 0, 0);                                \
        } while (0)

    STAGE(0, 0);

    #pragma unroll 1
    for (int it = 0; it < 16; ++it) {
        #pragma unroll
        for (int sub = 0; sub < 2; ++sub) {
            const int t = it * 2 + sub;
            const bool last = (t == 31);
            const unsigned char* As = Als[sub];
            const unsigned char* Ks = Kls[sub];
            const unsigned char* Vs = Vls[sub];

            if (!last) { STAGE(t + 1, sub ^ 1); VMW(4); } else { VMW(0); }
            SCHB();
            SBAR();

            i32x8 a8[4], bk8, bv8;
            #pragma unroll
            for (int mf = 0; mf < 4; ++mf) {
                i32x4 lo = *(const i32x4*)(As + abase + mf * 2048);
                i32x4 hi = *(const i32x4*)(As + abase + mf * 2048 + 1024);
                a8[mf] = __builtin_shufflevector(lo, hi, 0, 1, 2, 3, 4, 5, 6, 7);
            }
            {
                i32x4 lo = *(const i32x4*)(Ks + bbase);
                i32x4 hi = *(const i32x4*)(Ks + bbase + 1024);
                bk8 = __builtin_shufflevector(lo, hi, 0, 1, 2, 3, 4, 5, 6, 7);
            }
            __builtin_amdgcn_s_setprio(1);
            #pragma unroll
            for (int mf = 0; mf < 4; ++mf)
                accK[mf] = __builtin_amdgcn_mfma_scale_f32_32x32x64_f8f6f4(
                    a8[mf], bk8, accK[mf], 0, 0, 0, 0x7F7F7F7F, 0, 0x7B7B7B7B);
            __builtin_amdgcn_s_setprio(0);

            {
                i32x4 lo = *(const i32x4*)(Vs + bbase);
                i32x4 hi = *(const i32x4*)(Vs + bbase + 1024);
                bv8 = __builtin_shufflevector(lo, hi, 0, 1, 2, 3, 4, 5, 6, 7);
            }
            __builtin_amdgcn_s_setprio(1);
            #pragma unroll
            for (int mf = 0; mf < 4; ++mf)
                accV[mf] = __builtin_amdgcn_mfma_scale_f32_32x32x64_f8f6f4(
                    a8[mf], bv8, accV[mf], 0, 0, 0, 0x7F7F7F7F, 0, 0x7B7B7B7B);
            __builtin_amdgcn_s_setprio(0);
            SBAR();
        }
    }

    // ---- epilogue: bias, rotary, cos*cos, reduce over rows, atomicAdd
    // C/D (32x32): col = lane&31, row = (reg&3) + 8*(reg>>2) + 4*lh
    const int batch = row0 >> 12;
    const int c     = n0 + wc * 32 + l31;
    const float bK  = bias[c];
    const float bV  = bias[c + 2048];
    const bool rot  = (c < 1024);
    const float invf = exp2f((float)(c >> 1) * NEG_L2K);
    const float sgn  = (c & 1) ? 1.0f : -1.0f;
    const int sbase  = (row0 & 4095) + wrh * 128 + 4 * lh;

    float colsum = 0.0f;
    #pragma unroll
    for (int mf = 0; mf < 4; ++mf) {
        #pragma unroll
        for (int r = 0; r < 16; ++r) {
            const int srow = sbase + mf * 32 + (r & 3) + 8 * (r >> 2);
            float kv = accK[mf][r] + bK;
            float vv = accV[mf][r] + bV;
            float pk = __shfl_xor(kv, 1);
            float pv = __shfl_xor(vv, 1);
            float kr = kv, vr = vv;
            if (rot) {
                float sn, cs;
                __sincosf((float)srow * invf, &sn, &cs);
                float tt = sgn * sn;
                kr = kv * cs + pk * tt;
                vr = vv * cs + pv * tt;
            }
            colsum += __cosf(kr) * __cosf(vr);
        }
    }
    colsum += __shfl_xor(colsum, 32);
    if (lane < 32)
        atomicAdd(&A[batch * 2048 + c], colsum);
}

// ---------------- Kernel 4: out = (0.5*A + 0.5) * X --------------------
__global__ void scale_out_kernel(const float* __restrict__ X,
                                 const float* __restrict__ A,
                                 float* __restrict__ out, int n4) {
    int gid = blockIdx.x * blockDim.x + threadIdx.x;
    int stride = gridDim.x * blockDim.x;
    for (int i = gid; i < n4; i += stride) {
        int e0 = i * 4;
        int b  = e0 >> 23;        // S*D = 2^23
        int d  = e0 & 2047;
        float4 a4 = *(const float4*)(A + b * 2048 + d);
        float4 x4 = ((const float4*)X)[i];
        float4 o;
        o.x = (0.5f * a4.x + 0.5f) * x4.x;
        o.y = (0.5f * a4.y + 0.5f) * x4.y;
        o.z = (0.5f * a4.z + 0.5f) * x4.z;
        o.w = (0.5f * a4.w + 0.5f) * x4.w;
        ((float4*)out)[i] = o;
    }
}

extern "C" void kernel_launch(void* const* d_in, const int* in_sizes, int n_in,
                              void* d_out, int out_size, void* d_ws, size_t ws_size,
                              hipStream_t stream) {
    const float* X    = (const float*)d_in[0];   // [4][4096][2048]
    const float* W    = (const float*)d_in[1];   // [2048][4096]
    const float* bias = (const float*)d_in[2];   // [4096]
    float* out = (float*)d_out;

    const size_t szA  = 32768;                        // 4*2048*4 (padded)
    const size_t szWf = (size_t)4096 * 2048;          // 8.4 MB fp8
    const size_t szXf = (size_t)16384 * 2048;         // 33.5 MB fp8

    char* ws = (char*)d_ws;
    float* A = (float*)ws;                            // assume ws >= 32 KB
    unsigned char* Wf;
    unsigned char* Xf;
    if (ws_size >= szA + szWf + szXf) {
        Wf = (unsigned char*)(ws + szA);
        Xf = (unsigned char*)(ws + szA + szWf);
    } else if (ws_size >= szA + szWf) {
        Wf = (unsigned char*)(ws + szA);
        Xf = (unsigned char*)d_out;                   // scratch; rewritten by kernel 4
    } else {
        Xf = (unsigned char*)d_out;
        Wf = (unsigned char*)d_out + szXf;            // 42 MB <= 134 MB
    }

    prep_x_kernel<<<8192, 256, 0, stream>>>(X, Xf, A);
    prep_w_kernel<<<dim3(64, 32), 256, 0, stream>>>(W, Wf);
    gemm_acos_kernel<<<1024, 512, 0, stream>>>(Xf, Wf, bias, A);
    scale_out_kernel<<<2048, 256, 0, stream>>>(X, A, out, 16384 * 2048 / 4);
}

// Round 8
// 231.862 us; speedup vs baseline: 1.5168x; 1.0153x over previous
//
#include <hip/hip_runtime.h>
#include <hip/hip_bf16.h>

typedef __attribute__((ext_vector_type(4)))  int   i32x4;
typedef __attribute__((ext_vector_type(8)))  int   i32x8;
typedef __attribute__((ext_vector_type(16))) float f32x16;

#define NEG_L2K (-0.025952563241307517f)  // -log2(10000)/512

#define VMW(N) asm volatile("s_waitcnt vmcnt(" #N ")" ::: "memory")
#define SCHB() __builtin_amdgcn_sched_barrier(0)
#define SBAR() __builtin_amdgcn_s_barrier()

#define AS1 __attribute__((address_space(1)))
#define AS3 __attribute__((address_space(3)))

__device__ __forceinline__ unsigned int pk4_fp8(float a, float b, float c, float d) {
    unsigned int v = __builtin_amdgcn_cvt_pk_fp8_f32(a, b, 0, false);
    v = __builtin_amdgcn_cvt_pk_fp8_f32(c, d, v, true);
    return v;
}

// ---------------- Kernel 1: X fp32 -> fp8, fragment-major, BM=128 tiles ----
// Tile (mtile,kt) = 8192 B at (mtile*32+kt)*8192.  Chunk s*64+lane (16 B):
// s = mf*2+rd; bytes = fp8(X[mtile*128+mf*32+(lane&31)][kt*64+(lane>>5)*32+rd*16 ..+16])
__global__ __launch_bounds__(256) void prep_x_kernel(const float* __restrict__ X,
                                                     unsigned char* __restrict__ Xf,
                                                     float* __restrict__ A) {
    int g = blockIdx.x * 256 + threadIdx.x;   // 0 .. 2^21-1
    if (g < 8192) A[g] = 0.0f;
    int tileid = g >> 9;       // 0..4095
    int mtile  = tileid >> 5;  // 0..127
    int kt     = tileid & 31;
    int c      = g & 511;
    int s      = c >> 6;       // 0..7 = mf*2+rd
    int lane   = c & 63;
    int row  = mtile * 128 + (s >> 1) * 32 + (lane & 31);
    int kcol = kt * 64 + (lane >> 5) * 32 + (s & 1) * 16;
    const float* src = X + (size_t)row * 2048 + kcol;
    float4 f0 = *(const float4*)(src);
    float4 f1 = *(const float4*)(src + 4);
    float4 f2 = *(const float4*)(src + 8);
    float4 f3 = *(const float4*)(src + 12);
    uint4 o;
    o.x = pk4_fp8(f0.x, f0.y, f0.z, f0.w);
    o.y = pk4_fp8(f1.x, f1.y, f1.z, f1.w);
    o.z = pk4_fp8(f2.x, f2.y, f2.z, f2.w);
    o.w = pk4_fp8(f3.x, f3.y, f3.z, f3.w);
    *(uint4*)(Xf + (size_t)g * 16) = o;
}

// ---------------- Kernel 2: W fp32 -> fp8 (x16 pre-scale) frag-major -------
// (verified in R7 — unchanged)  Out tile (ntile,kt,KV) = 8 KB at
// ((ntile*32+kt)*2+KV)*8192; chunk (wc*2+rd)*64+lane holds
// W[kt*64+(lane>>5)*32+rd*16 ..+16][ntile*128+wc*32+(lane&31)]*16
__global__ __launch_bounds__(256) void prep_w_kernel(const float* __restrict__ W,
                                                     unsigned char* __restrict__ Wf) {
    __shared__ unsigned char t[64][72];
    int f0 = blockIdx.x * 64;   // along 4096 (f)
    int k0 = blockIdx.y * 64;   // along 2048 (k)
    int tx = threadIdx.x & 63;
    int ty = threadIdx.x >> 6;
    for (int r = ty; r < 64; r += 4) {
        float w = W[(size_t)(k0 + r) * 4096 + f0 + tx] * 16.0f;
        t[r][tx] = (unsigned char)(__builtin_amdgcn_cvt_pk_fp8_f32(w, w, 0, false) & 0xFF);
    }
    __syncthreads();
    int c   = threadIdx.x;
    int il  = c & 31;
    int lh  = (c >> 5) & 1;
    int rd  = (c >> 6) & 1;
    int wcl = c >> 7;
    int col_l = wcl * 32 + il;          // 0..63 within block
    int kl    = lh * 32 + rd * 16;
    int fh    = f0 & 2047;
    int KV    = f0 >> 11;
    int ntile = fh >> 7;
    int wcg   = ((fh >> 5) & 2) + wcl;
    union { unsigned char b[16]; uint4 v; } ob;
    #pragma unroll
    for (int b = 0; b < 16; ++b) ob.b[b] = t[kl + b][col_l];
    size_t base = ((((size_t)ntile * 32 + blockIdx.y) * 2 + KV) << 13)
                + (size_t)(((wcg * 2 + rd) * 64 + lh * 32 + il) << 4);
    *(uint4*)(Wf + base) = ob.v;
}

// ---------------- Kernel 3: fused fp8 GEMM + rotary + cos*cos + reduce ----
// MX-fp8 mfma_scale 32x32x64.  4 waves/block, BM=128, 2 blocks/CU so two
// independent barrier schedules overlap per CU (LDS-read phase of one block
// hides under MFMA clusters of the other).  VMW(6) + 2 barriers per K-step.
__global__ __launch_bounds__(256, 2) void gemm_acos_kernel(
    const unsigned char* __restrict__ Xf,
    const unsigned char* __restrict__ Wf,
    const float* __restrict__ bias,
    float* __restrict__ A)
{
    __shared__ __align__(16) unsigned char Als[2][8192];
    __shared__ __align__(16) unsigned char Kls[2][8192];
    __shared__ __align__(16) unsigned char Vls[2][8192];

    const int tid  = threadIdx.x;
    const int lane = tid & 63;
    const int wc   = tid >> 6;    // 0..3  col quarter (32 cols)
    const int l31  = lane & 31;
    const int lh   = lane >> 5;

    // T1: bijective XCD swizzle, grid 2048 = 128 mtiles x 16 ntiles
    const int orig  = blockIdx.x;
    const int wg    = (orig & 7) * 256 + (orig >> 3);
    const int mtile = wg & 127;
    const int ntile = wg >> 7;
    const int row0  = mtile * 128;
    const int n0    = ntile * 128;

    const unsigned char* XfT = Xf + ((size_t)(mtile * 32) << 13);
    const unsigned char* WfT = Wf + ((size_t)(ntile * 32) << 14);

    f32x16 accK[4] = {};
    f32x16 accV[4] = {};

    const int abase = lane * 16;                 // + mf*2048 + rd*1024
    const int bbase = (wc * 128 + lane) * 16;    // + rd*1024

    // stage one K-tile (A 8 KB, K 8 KB, V 8 KB) -> 6 loads/thread
    #define STAGE(T, NB)                                                                    \
        do {                                                                                \
            const unsigned char* ga = XfT + ((size_t)(T) << 13);                            \
            const unsigned char* gw = WfT + ((size_t)(T) << 14);                            \
            __builtin_amdgcn_global_load_lds((const AS1 void*)(ga + tid * 16),              \
                (AS3 void*)(Als[NB] + tid * 16), 16, 0, 0);                                 \
            __builtin_amdgcn_global_load_lds((const AS1 void*)(ga + 4096 + tid * 16),       \
                (AS3 void*)(Als[NB] + 4096 + tid * 16), 16, 0, 0);                          \
            __builtin_amdgcn_global_load_lds((const AS1 void*)(gw + tid * 16),              \
                (AS3 void*)(Kls[NB] + tid * 16), 16, 0, 0);                                 \
            __builtin_amdgcn_global_load_lds((const AS1 void*)(gw + 4096 + tid * 16),       \
                (AS3 void*)(Kls[NB] + 4096 + tid * 16), 16, 0, 0);                          \
            __builtin_amdgcn_global_load_lds((const AS1 void*)(gw + 8192 + tid * 16),       \
                (AS3 void*)(Vls[NB] + tid * 16), 16, 0, 0);                                 \
            __builtin_amdgcn_global_load_lds((const AS1 void*)(gw + 12288 + tid * 16),      \
                (AS3 void*)(Vls[NB] + 4096 + tid * 16), 16, 0, 0);                          \
        } while (0)

    STAGE(0, 0);

    #pragma unroll 1
    for (int it = 0; it < 16; ++it) {
        #pragma unroll
        for (int sub = 0; sub < 2; ++sub) {
            const int t = it * 2 + sub;
            const bool last = (t == 31);
            const unsigned char* As = Als[sub];
            const unsigned char* Ks = Kls[sub];
            const unsigned char* Vs = Vls[sub];

            if (!last) { STAGE(t + 1, sub ^ 1); VMW(6); } else { VMW(0); }
            SCHB();
            SBAR();

            i32x8 a8[4], bk8, bv8;
            #pragma unroll
            for (int mf = 0; mf < 4; ++mf) {
                i32x4 lo = *(const i32x4*)(As + abase + mf * 2048);
                i32x4 hi = *(const i32x4*)(As + abase + mf * 2048 + 1024);
                a8[mf] = __builtin_shufflevector(lo, hi, 0, 1, 2, 3, 4, 5, 6, 7);
            }
            {
                i32x4 lo = *(const i32x4*)(Ks + bbase);
                i32x4 hi = *(const i32x4*)(Ks + bbase + 1024);
                bk8 = __builtin_shufflevector(lo, hi, 0, 1, 2, 3, 4, 5, 6, 7);
            }
            __builtin_amdgcn_s_setprio(1);
            #pragma unroll
            for (int mf = 0; mf < 4; ++mf)
                accK[mf] = __builtin_amdgcn_mfma_scale_f32_32x32x64_f8f6f4(
                    a8[mf], bk8, accK[mf], 0, 0, 0, 0x7F7F7F7F, 0, 0x7B7B7B7B);
            __builtin_amdgcn_s_setprio(0);

            {
                i32x4 lo = *(const i32x4*)(Vs + bbase);
                i32x4 hi = *(const i32x4*)(Vs + bbase + 1024);
                bv8 = __builtin_shufflevector(lo, hi, 0, 1, 2, 3, 4, 5, 6, 7);
            }
            __builtin_amdgcn_s_setprio(1);
            #pragma unroll
            for (int mf = 0; mf < 4; ++mf)
                accV[mf] = __builtin_amdgcn_mfma_scale_f32_32x32x64_f8f6f4(
                    a8[mf], bv8, accV[mf], 0, 0, 0, 0x7F7F7F7F, 0, 0x7B7B7B7B);
            __builtin_amdgcn_s_setprio(0);
            SBAR();
        }
    }

    // ---- epilogue: bias, rotary, cos*cos, reduce over rows, atomicAdd
    // C/D (32x32): col = lane&31, row = (reg&3) + 8*(reg>>2) + 4*lh
    const int batch = row0 >> 12;
    const int c     = n0 + wc * 32 + l31;
    const float bK  = bias[c];
    const float bV  = bias[c + 2048];
    const bool rot  = (c < 1024);
    const float invf = exp2f((float)(c >> 1) * NEG_L2K);
    const float sgn  = (c & 1) ? 1.0f : -1.0f;
    const int sbase  = (row0 & 4095) + 4 * lh;

    float colsum = 0.0f;
    #pragma unroll
    for (int mf = 0; mf < 4; ++mf) {
        #pragma unroll
        for (int r = 0; r < 16; ++r) {
            const int srow = sbase + mf * 32 + (r & 3) + 8 * (r >> 2);
            float kv = accK[mf][r] + bK;
            float vv = accV[mf][r] + bV;
            float pk = __shfl_xor(kv, 1);
            float pv = __shfl_xor(vv, 1);
            float kr = kv, vr = vv;
            if (rot) {
                float sn, cs;
                __sincosf((float)srow * invf, &sn, &cs);
                float tt = sgn * sn;
                kr = kv * cs + pk * tt;
                vr = vv * cs + pv * tt;
            }
            colsum += __cosf(kr) * __cosf(vr);
        }
    }
    colsum += __shfl_xor(colsum, 32);
    if (lane < 32)
        atomicAdd(&A[batch * 2048 + c], colsum);
}

// ---------------- Kernel 4: out = (0.5*A + 0.5) * X --------------------
__global__ void scale_out_kernel(const float* __restrict__ X,
                                 const float* __restrict__ A,
                                 float* __restrict__ out, int n4) {
    int gid = blockIdx.x * blockDim.x + threadIdx.x;
    int stride = gridDim.x * blockDim.x;
    for (int i = gid; i < n4; i += stride) {
        int e0 = i * 4;
        int b  = e0 >> 23;        // S*D = 2^23
        int d  = e0 & 2047;
        float4 a4 = *(const float4*)(A + b * 2048 + d);
        float4 x4 = ((const float4*)X)[i];
        float4 o;
        o.x = (0.5f * a4.x + 0.5f) * x4.x;
        o.y = (0.5f * a4.y + 0.5f) * x4.y;
        o.z = (0.5f * a4.z + 0.5f) * x4.z;
        o.w = (0.5f * a4.w + 0.5f) * x4.w;
        ((float4*)out)[i] = o;
    }
}

extern "C" void kernel_launch(void* const* d_in, const int* in_sizes, int n_in,
                              void* d_out, int out_size, void* d_ws, size_t ws_size,
                              hipStream_t stream) {
    const float* X    = (const float*)d_in[0];   // [4][4096][2048]
    const float* W    = (const float*)d_in[1];   // [2048][4096]
    const float* bias = (const float*)d_in[2];   // [4096]
    float* out = (float*)d_out;

    const size_t szA  = 32768;                        // 4*2048*4 (padded)
    const size_t szWf = (size_t)4096 * 2048;          // 8.4 MB fp8
    const size_t szXf = (size_t)16384 * 2048;         // 33.5 MB fp8

    char* ws = (char*)d_ws;
    float* A = (float*)ws;                            // assume ws >= 32 KB
    unsigned char* Wf;
    unsigned char* Xf;
    if (ws_size >= szA + szWf + szXf) {
        Wf = (unsigned char*)(ws + szA);
        Xf = (unsigned char*)(ws + szA + szWf);
    } else if (ws_size >= szA + szWf) {
        Wf = (unsigned char*)(ws + szA);
        Xf = (unsigned char*)d_out;                   // scratch; rewritten by kernel 4
    } else {
        Xf = (unsigned char*)d_out;
        Wf = (unsigned char*)d_out + szXf;            // 42 MB <= 134 MB
    }

    prep_x_kernel<<<8192, 256, 0, stream>>>(X, Xf, A);
    prep_w_kernel<<<dim3(64, 32), 256, 0, stream>>>(W, Wf);
    gemm_acos_kernel<<<2048, 256, 0, stream>>>(Xf, Wf, bias, A);
    scale_out_kernel<<<2048, 256, 0, stream>>>(X, A, out, 16384 * 2048 / 4);
}